// Round 1
// baseline (1165.341 us; speedup 1.0000x reference)
//
#include <hip/hip_runtime.h>

#define NN 20000
#define EE 320000
#define GG 50
#define IN_ 64
#define H1_ 10
#define D1_ 64
#define D2_ 128
#define F1 640   /* H1_*D1_ */
#define NEG 0.2f

static inline int cdiv(long long a, int b){ return (int)((a + b - 1) / b); }

__device__ inline unsigned fenc(float f){
  unsigned b = __float_as_uint(f);
  return (b & 0x80000000u) ? ~b : (b | 0x80000000u);
}
__device__ inline float fdec(unsigned k){
  unsigned b = (k & 0x80000000u) ? (k & 0x7FFFFFFFu) : ~k;
  return __uint_as_float(b);
}
__device__ inline float lrelu(float x){ return x > 0.f ? x : NEG * x; }
__device__ inline float wred(float x){
  #pragma unroll
  for(int off = 32; off > 0; off >>= 1) x += __shfl_down(x, off, 64);
  return x;
}

__global__ void fill_f32(float* p, float v, int n){
  int i = blockIdx.x * blockDim.x + threadIdx.x;
  if(i < n) p[i] = v;
}
__global__ void fill_u32(unsigned* p, unsigned v, int n){
  int i = blockIdx.x * blockDim.x + threadIdx.x;
  if(i < n) p[i] = v;
}

// ft1[n, j] = sum_k feat[n,k] * W1[k,j]   (j in [0,640))
__global__ void gemm_ft1(const float* __restrict__ feat, const float* __restrict__ W1,
                         float* __restrict__ ft1){
  __shared__ float arow[IN_];
  int n = blockIdx.y;
  int j = blockIdx.x * 320 + threadIdx.x;
  if(threadIdx.x < IN_) arow[threadIdx.x] = feat[n * IN_ + threadIdx.x];
  __syncthreads();
  if(j >= F1) return;
  float acc = 0.f;
  #pragma unroll
  for(int k = 0; k < IN_; k++) acc += arow[k] * W1[k * F1 + j];
  ft1[(size_t)n * F1 + j] = acc;
}

// el/er per (node, head): wave per (n,h), lane = d
__global__ void elr1_kernel(const float* __restrict__ ft1, const float* __restrict__ al,
                            const float* __restrict__ ar, float* __restrict__ el,
                            float* __restrict__ er){
  int gw = (blockIdx.x * blockDim.x + threadIdx.x) >> 6;
  int lane = threadIdx.x & 63;
  if(gw >= NN * H1_) return;
  int n = gw / H1_, h = gw % H1_;
  float v = ft1[(size_t)n * F1 + h * D1_ + lane];
  float e1 = wred(v * al[h * D1_ + lane]);
  float e2 = wred(v * ar[h * D1_ + lane]);
  if(lane == 0){ el[n * H1_ + h] = e1; er[n * H1_ + h] = e2; }
}

__global__ void emax1(const int* __restrict__ src, const int* __restrict__ dst,
                      const float* __restrict__ el, const float* __restrict__ er,
                      unsigned* __restrict__ m){
  int i = blockIdx.x * blockDim.x + threadIdx.x;
  if(i >= EE * H1_) return;
  int e = i / H1_, h = i - e * H1_;
  int dn = dst[e];
  float x = lrelu(el[src[e] * H1_ + h] + er[dn * H1_ + h]);
  atomicMax(&m[dn * H1_ + h], fenc(x));
}

__global__ void esum1(const int* __restrict__ src, const int* __restrict__ dst,
                      const float* __restrict__ el, const float* __restrict__ er,
                      const unsigned* __restrict__ m, float* __restrict__ s){
  int i = blockIdx.x * blockDim.x + threadIdx.x;
  if(i >= EE * H1_) return;
  int e = i / H1_, h = i - e * H1_;
  int dn = dst[e];
  float x = lrelu(el[src[e] * H1_ + h] + er[dn * H1_ + h]);
  float ex = expf(x - fdec(m[dn * H1_ + h]));
  atomicAdd(&s[dn * H1_ + h], ex);
}

// wave per (edge, head); lane = d; out1[dn,h,d] += ft1[sn,h,d] * a
__global__ void eagg1(const int* __restrict__ src, const int* __restrict__ dst,
                      const float* __restrict__ el, const float* __restrict__ er,
                      const unsigned* __restrict__ m, const float* __restrict__ s,
                      const float* __restrict__ ft1, float* __restrict__ out1){
  long long gt = (long long)blockIdx.x * blockDim.x + threadIdx.x;
  long long gw = gt >> 6;
  int lane = threadIdx.x & 63;
  if(gw >= (long long)EE * H1_) return;
  int e = (int)(gw / H1_), h = (int)(gw % H1_);
  int sn = src[e], dn = dst[e];
  float x = lrelu(el[sn * H1_ + h] + er[dn * H1_ + h]);
  float a = expf(x - fdec(m[dn * H1_ + h])) / s[dn * H1_ + h];
  atomicAdd(&out1[(size_t)dn * F1 + h * D1_ + lane],
            ft1[(size_t)sn * F1 + h * D1_ + lane] * a);
}

// h1[n,d] = sum_h relu(out1[n,h,d] + b1[h,d])
__global__ void relu_sum_heads(const float* __restrict__ out1, const float* __restrict__ b1,
                               float* __restrict__ h1v){
  int i = blockIdx.x * blockDim.x + threadIdx.x;
  if(i >= NN * D1_) return;
  int n = i >> 6, d = i & 63;
  float acc = 0.f;
  #pragma unroll
  for(int h = 0; h < H1_; h++){
    float v = out1[(size_t)n * F1 + h * D1_ + d] + b1[h * D1_ + d];
    acc += v > 0.f ? v : 0.f;
  }
  h1v[i] = acc;
}

// ft2[n, j] = sum_k h1[n,k] * W2[k,j]  (j in [0,128))
__global__ void gemm_ft2(const float* __restrict__ h1v, const float* __restrict__ W2,
                         float* __restrict__ ft2){
  __shared__ float arow[D1_];
  int n = blockIdx.x;
  int j = threadIdx.x;
  if(j < D1_) arow[j] = h1v[n * D1_ + j];
  __syncthreads();
  float acc = 0.f;
  #pragma unroll
  for(int k = 0; k < D1_; k++) acc += arow[k] * W2[k * D2_ + j];
  ft2[(size_t)n * D2_ + j] = acc;
}

__global__ void elr2_kernel(const float* __restrict__ ft2, const float* __restrict__ al,
                            const float* __restrict__ ar, float* __restrict__ el,
                            float* __restrict__ er){
  int gw = (blockIdx.x * blockDim.x + threadIdx.x) >> 6;
  int lane = threadIdx.x & 63;
  if(gw >= NN) return;
  float v0 = ft2[(size_t)gw * D2_ + lane];
  float v1 = ft2[(size_t)gw * D2_ + 64 + lane];
  float e1 = wred(v0 * al[lane] + v1 * al[64 + lane]);
  float e2 = wred(v0 * ar[lane] + v1 * ar[64 + lane]);
  if(lane == 0){ el[gw] = e1; er[gw] = e2; }
}

__global__ void emax2(const int* __restrict__ src, const int* __restrict__ dst,
                      const float* __restrict__ el, const float* __restrict__ er,
                      unsigned* __restrict__ m){
  int e = blockIdx.x * blockDim.x + threadIdx.x;
  if(e >= EE) return;
  int dn = dst[e];
  float x = lrelu(el[src[e]] + er[dn]);
  atomicMax(&m[dn], fenc(x));
}

__global__ void esum2(const int* __restrict__ src, const int* __restrict__ dst,
                      const float* __restrict__ el, const float* __restrict__ er,
                      const unsigned* __restrict__ m, float* __restrict__ s){
  int e = blockIdx.x * blockDim.x + threadIdx.x;
  if(e >= EE) return;
  int dn = dst[e];
  float x = lrelu(el[src[e]] + er[dn]);
  atomicAdd(&s[dn], expf(x - fdec(m[dn])));
}

// wave per (edge, half of D2)
__global__ void eagg2(const int* __restrict__ src, const int* __restrict__ dst,
                      const float* __restrict__ el, const float* __restrict__ er,
                      const unsigned* __restrict__ m, const float* __restrict__ s,
                      const float* __restrict__ ft2, float* __restrict__ agg2){
  long long gt = (long long)blockIdx.x * blockDim.x + threadIdx.x;
  long long gw = gt >> 6;
  int lane = threadIdx.x & 63;
  if(gw >= 2LL * EE) return;
  int e = (int)(gw >> 1);
  int d = (int)((gw & 1) << 6) + lane;
  int sn = src[e], dn = dst[e];
  float x = lrelu(el[sn] + er[dn]);
  float a = expf(x - fdec(m[dn])) / s[dn];
  atomicAdd(&agg2[(size_t)dn * D2_ + d], ft2[(size_t)sn * D2_ + d] * a);
}

// per-graph max of relu(agg2 + b2): values >= 0, so int atomicMax with 0-init is exact
__global__ void readout_max(const float* __restrict__ agg2, const float* __restrict__ b2,
                            const int* __restrict__ gid, int* __restrict__ r){
  int i = blockIdx.x * blockDim.x + threadIdx.x;
  if(i >= NN * D2_) return;
  int n = i >> 7, d = i & 127;
  float v = agg2[i] + b2[d];
  v = v > 0.f ? v : 0.f;
  atomicMax(&r[gid[n] * D2_ + d], __float_as_int(v));
}

__global__ void final_mlp(const float* __restrict__ r, const float* __restrict__ lw1,
                          const float* __restrict__ lb1, const float* __restrict__ lw2,
                          const float* __restrict__ lb2, float* __restrict__ out){
  __shared__ float rv[D2_];
  __shared__ float t[D2_];
  int g = blockIdx.x, j = threadIdx.x;
  rv[j] = r[g * D2_ + j];
  __syncthreads();
  float acc = lb1[j];
  #pragma unroll
  for(int k = 0; k < D2_; k++) acc += rv[k] * lw1[k * D2_ + j];
  acc = acc > 0.f ? acc : 0.f;
  t[j] = acc * lw2[j];
  __syncthreads();
  for(int off = 64; off > 0; off >>= 1){
    if(j < off) t[j] += t[j + off];
    __syncthreads();
  }
  if(j == 0){
    float v = t[0] + lb2[0];
    out[g] = v > 0.f ? v : 0.f;
  }
}

extern "C" void kernel_launch(void* const* d_in, const int* in_sizes, int n_in,
                              void* d_out, int out_size, void* d_ws, size_t ws_size,
                              hipStream_t stream) {
  const float* feat = (const float*)d_in[0];
  const int*   src  = (const int*)d_in[1];
  const int*   dst  = (const int*)d_in[2];
  const int*   gid  = (const int*)d_in[3];
  const float* W1   = (const float*)d_in[4];
  const float* al1  = (const float*)d_in[5];
  const float* ar1  = (const float*)d_in[6];
  const float* b1   = (const float*)d_in[7];
  const float* W2   = (const float*)d_in[8];
  const float* al2  = (const float*)d_in[9];
  const float* ar2  = (const float*)d_in[10];
  const float* b2   = (const float*)d_in[11];
  const float* lw1  = (const float*)d_in[12];
  const float* lb1  = (const float*)d_in[13];
  const float* lw2  = (const float*)d_in[14];
  const float* lb2  = (const float*)d_in[15];
  float* out = (float*)d_out;

  float* ws = (float*)d_ws;
  size_t o = 0;
  float* ft1  = ws + o; o += (size_t)NN * F1;    // 12.8M
  float* out1 = ws + o; o += (size_t)NN * F1;    // 12.8M
  float* el1  = ws + o; o += (size_t)NN * H1_;
  float* er1  = ws + o; o += (size_t)NN * H1_;
  unsigned* m1 = (unsigned*)(ws + o); o += (size_t)NN * H1_;
  float* s1   = ws + o; o += (size_t)NN * H1_;
  float* h1v  = ws + o; o += (size_t)NN * D1_;
  float* el2  = ws + o; o += NN;
  float* er2  = ws + o; o += NN;
  unsigned* m2 = (unsigned*)(ws + o); o += NN;
  float* s2   = ws + o; o += NN;
  float* rbuf = ws + o; o += (size_t)GG * D2_;
  // aliases: layer-1 big buffers are dead by the time these are written
  float* ft2  = ft1;    // NN*D2_ <= NN*F1
  float* agg2 = out1;   // NN*D2_ <= NN*F1

  const unsigned ENC_NEG_INF = 0x007FFFFFu;  // fenc(-inf)

  // ---- layer 1 ----
  fill_u32<<<cdiv(NN*H1_,256),256,0,stream>>>(m1, ENC_NEG_INF, NN*H1_);
  fill_f32<<<cdiv(NN*H1_,256),256,0,stream>>>(s1, 0.f, NN*H1_);
  fill_f32<<<cdiv((long long)NN*F1,256),256,0,stream>>>(out1, 0.f, NN*F1);

  gemm_ft1<<<dim3(2, NN), 320, 0, stream>>>(feat, W1, ft1);
  elr1_kernel<<<cdiv((long long)NN*H1_*64,256),256,0,stream>>>(ft1, al1, ar1, el1, er1);
  emax1<<<cdiv((long long)EE*H1_,256),256,0,stream>>>(src, dst, el1, er1, m1);
  esum1<<<cdiv((long long)EE*H1_,256),256,0,stream>>>(src, dst, el1, er1, m1, s1);
  eagg1<<<cdiv((long long)EE*H1_*64,256),256,0,stream>>>(src, dst, el1, er1, m1, s1, ft1, out1);
  relu_sum_heads<<<cdiv((long long)NN*D1_,256),256,0,stream>>>(out1, b1, h1v);

  // ---- layer 2 (ft2 aliases ft1, agg2 aliases out1) ----
  fill_u32<<<cdiv(NN,256),256,0,stream>>>(m2, ENC_NEG_INF, NN);
  fill_f32<<<cdiv(NN,256),256,0,stream>>>(s2, 0.f, NN);
  fill_f32<<<cdiv((long long)NN*D2_,256),256,0,stream>>>(agg2, 0.f, NN*D2_);

  gemm_ft2<<<NN, 128, 0, stream>>>(h1v, W2, ft2);
  elr2_kernel<<<cdiv((long long)NN*64,256),256,0,stream>>>(ft2, al2, ar2, el2, er2);
  emax2<<<cdiv(EE,256),256,0,stream>>>(src, dst, el2, er2, m2);
  esum2<<<cdiv(EE,256),256,0,stream>>>(src, dst, el2, er2, m2, s2);
  eagg2<<<cdiv(2LL*EE*64,256),256,0,stream>>>(src, dst, el2, er2, m2, s2, ft2, agg2);

  // ---- readout + MLP ----
  fill_f32<<<cdiv(GG*D2_,256),256,0,stream>>>(rbuf, 0.f, GG*D2_);
  readout_max<<<cdiv((long long)NN*D2_,256),256,0,stream>>>(agg2, b2, gid, (int*)rbuf);
  final_mlp<<<GG, D2_, 0, stream>>>(rbuf, lw1, lb1, lw2, lb2, out);
}

// Round 2
// 613.734 us; speedup vs baseline: 1.8988x; 1.8988x over previous
//
#include <hip/hip_runtime.h>

#define NN 20000
#define EE 320000
#define GG 50
#define IN_ 64
#define H1_ 10
#define D1_ 64
#define D2_ 128
#define F1 640   /* H1_*D1_ */
#define NEG 0.2f

static inline int cdiv(long long a, int b){ return (int)((a + b - 1) / b); }

__device__ inline float lrelu(float x){ return x > 0.f ? x : NEG * x; }
__device__ inline float wmax64(float x){
  #pragma unroll
  for(int off = 32; off > 0; off >>= 1) x = fmaxf(x, __shfl_xor(x, off, 64));
  return x;
}
__device__ inline float wsum64(float x){
  #pragma unroll
  for(int off = 32; off > 0; off >>= 1) x += __shfl_xor(x, off, 64);
  return x;
}

__global__ void fill_u32(unsigned* p, unsigned v, int n){
  int i = blockIdx.x * blockDim.x + threadIdx.x;
  if(i < n) p[i] = v;
}

// ---------------- CSR build (dst-sorted src list) ----------------
__global__ void hist_k(const int* __restrict__ dst, int* __restrict__ hist){
  int e = blockIdx.x * blockDim.x + threadIdx.x;
  if(e < EE) atomicAdd(&hist[dst[e]], 1);
}

// single block, 1024 threads, 20 elements each
__global__ void scan_k(const int* __restrict__ hist, int* __restrict__ rowptr,
                       int* __restrict__ cursor){
  __shared__ int tot[1024];
  int t = threadIdx.x;
  int vals[20];
  int s = 0;
  #pragma unroll
  for(int i = 0; i < 20; i++){
    int idx = t * 20 + i;
    int v = idx < NN ? hist[idx] : 0;
    vals[i] = v; s += v;
  }
  tot[t] = s;
  __syncthreads();
  for(int off = 1; off < 1024; off <<= 1){
    int v = t >= off ? tot[t - off] : 0;
    __syncthreads();
    tot[t] += v;
    __syncthreads();
  }
  int run = tot[t] - s;  // exclusive prefix
  #pragma unroll
  for(int i = 0; i < 20; i++){
    int idx = t * 20 + i;
    if(idx < NN){ rowptr[idx] = run; cursor[idx] = run; run += vals[i]; }
  }
  if(t == 1023) rowptr[NN] = tot[1023];
}

__global__ void scatter_k(const int* __restrict__ src, const int* __restrict__ dst,
                          int* __restrict__ cursor, int* __restrict__ ssrc){
  int e = blockIdx.x * blockDim.x + threadIdx.x;
  if(e >= EE) return;
  int pos = atomicAdd(&cursor[dst[e]], 1);
  ssrc[pos] = src[e];
}

// ---------------- layer-1 dense parts ----------------
__global__ void gemm_ft1(const float* __restrict__ feat, const float* __restrict__ W1,
                         float* __restrict__ ft1){
  __shared__ float arow[IN_];
  int n = blockIdx.y;
  int j = blockIdx.x * 320 + threadIdx.x;
  if(threadIdx.x < IN_) arow[threadIdx.x] = feat[n * IN_ + threadIdx.x];
  __syncthreads();
  if(j >= F1) return;
  float acc = 0.f;
  #pragma unroll
  for(int k = 0; k < IN_; k++) acc += arow[k] * W1[k * F1 + j];
  ft1[(size_t)n * F1 + j] = acc;
}

__global__ void elr1_kernel(const float* __restrict__ ft1, const float* __restrict__ al,
                            const float* __restrict__ ar, float* __restrict__ el,
                            float* __restrict__ er){
  int gw = (blockIdx.x * blockDim.x + threadIdx.x) >> 6;
  int lane = threadIdx.x & 63;
  if(gw >= NN * H1_) return;
  int n = gw / H1_, h = gw % H1_;
  float v = ft1[(size_t)n * F1 + h * D1_ + lane];
  float e1 = wsum64(v * al[h * D1_ + lane]);
  float e2 = wsum64(v * ar[h * D1_ + lane]);
  if(lane == 0){ el[n * H1_ + h] = e1; er[n * H1_ + h] = e2; }
}

// fused softmax + aggregation + bias + relu + head-sum; block = 640 (wave per head)
__global__ void l1_agg(const int* __restrict__ rowptr, const int* __restrict__ ssrc,
                       const float* __restrict__ el, const float* __restrict__ er,
                       const float* __restrict__ ft1, const float* __restrict__ b1,
                       float* __restrict__ h1v){
  __shared__ float sdata[F1];
  int dn = blockIdx.x;
  int h = threadIdx.x >> 6, lane = threadIdx.x & 63;
  int base = rowptr[dn], deg = rowptr[dn + 1] - base;
  float er_h = er[dn * H1_ + h];
  float mx = -INFINITY;
  for(int i = lane; i < deg; i += 64){
    int sn = ssrc[base + i];
    mx = fmaxf(mx, lrelu(el[sn * H1_ + h] + er_h));
  }
  mx = wmax64(mx);
  float sm = 0.f;
  for(int i = lane; i < deg; i += 64){
    int sn = ssrc[base + i];
    sm += expf(lrelu(el[sn * H1_ + h] + er_h) - mx);
  }
  sm = wsum64(sm);
  float inv = deg > 0 ? 1.f / sm : 0.f;
  float acc = 0.f;
  for(int i = 0; i < deg; i++){
    int sn = ssrc[base + i];  // wave-uniform -> broadcast
    float a = expf(lrelu(el[sn * H1_ + h] + er_h) - mx) * inv;
    acc += a * ft1[(size_t)sn * F1 + h * D1_ + lane];
  }
  float v = acc + b1[h * D1_ + lane];
  sdata[h * D1_ + lane] = v > 0.f ? v : 0.f;
  __syncthreads();
  if(h == 0){
    float s = 0.f;
    #pragma unroll
    for(int hh = 0; hh < H1_; hh++) s += sdata[hh * D1_ + lane];
    h1v[dn * D1_ + lane] = s;
  }
}

// ---------------- layer-2 dense parts ----------------
__global__ void gemm_ft2(const float* __restrict__ h1v, const float* __restrict__ W2,
                         float* __restrict__ ft2){
  __shared__ float arow[D1_];
  int n = blockIdx.x;
  int j = threadIdx.x;
  if(j < D1_) arow[j] = h1v[n * D1_ + j];
  __syncthreads();
  float acc = 0.f;
  #pragma unroll
  for(int k = 0; k < D1_; k++) acc += arow[k] * W2[k * D2_ + j];
  ft2[(size_t)n * D2_ + j] = acc;
}

__global__ void elr2_kernel(const float* __restrict__ ft2, const float* __restrict__ al,
                            const float* __restrict__ ar, float* __restrict__ el,
                            float* __restrict__ er){
  int gw = (blockIdx.x * blockDim.x + threadIdx.x) >> 6;
  int lane = threadIdx.x & 63;
  if(gw >= NN) return;
  float v0 = ft2[(size_t)gw * D2_ + lane];
  float v1 = ft2[(size_t)gw * D2_ + 64 + lane];
  float e1 = wsum64(v0 * al[lane] + v1 * al[64 + lane]);
  float e2 = wsum64(v0 * ar[lane] + v1 * ar[64 + lane]);
  if(lane == 0){ el[gw] = e1; er[gw] = e2; }
}

// fused softmax + aggregation + bias + relu + per-graph max readout; block = 128
__global__ void l2_agg(const int* __restrict__ rowptr, const int* __restrict__ ssrc,
                       const float* __restrict__ el, const float* __restrict__ er,
                       const float* __restrict__ ft2, const float* __restrict__ b2,
                       const int* __restrict__ gid, int* __restrict__ rbuf){
  int dn = blockIdx.x;
  int d = threadIdx.x, lane = d & 63;
  int base = rowptr[dn], deg = rowptr[dn + 1] - base;
  float er_d = er[dn];
  float mx = -INFINITY;
  for(int i = lane; i < deg; i += 64)
    mx = fmaxf(mx, lrelu(el[ssrc[base + i]] + er_d));
  mx = wmax64(mx);
  float sm = 0.f;
  for(int i = lane; i < deg; i += 64)
    sm += expf(lrelu(el[ssrc[base + i]] + er_d) - mx);
  sm = wsum64(sm);
  float inv = deg > 0 ? 1.f / sm : 0.f;
  float acc = 0.f;
  for(int i = 0; i < deg; i++){
    int sn = ssrc[base + i];
    float a = expf(lrelu(el[sn] + er_d) - mx) * inv;
    acc += a * ft2[(size_t)sn * D2_ + d];
  }
  float v = acc + b2[d];
  v = v > 0.f ? v : 0.f;
  atomicMax(&rbuf[gid[dn] * D2_ + d], __float_as_int(v));  // v>=0: int order == float order
}

__global__ void final_mlp(const float* __restrict__ r, const float* __restrict__ lw1,
                          const float* __restrict__ lb1, const float* __restrict__ lw2,
                          const float* __restrict__ lb2, float* __restrict__ out){
  __shared__ float rv[D2_];
  __shared__ float t[D2_];
  int g = blockIdx.x, j = threadIdx.x;
  rv[j] = r[g * D2_ + j];
  __syncthreads();
  float acc = lb1[j];
  #pragma unroll
  for(int k = 0; k < D2_; k++) acc += rv[k] * lw1[k * D2_ + j];
  acc = acc > 0.f ? acc : 0.f;
  t[j] = acc * lw2[j];
  __syncthreads();
  for(int off = 64; off > 0; off >>= 1){
    if(j < off) t[j] += t[j + off];
    __syncthreads();
  }
  if(j == 0){
    float v = t[0] + lb2[0];
    out[g] = v > 0.f ? v : 0.f;
  }
}

extern "C" void kernel_launch(void* const* d_in, const int* in_sizes, int n_in,
                              void* d_out, int out_size, void* d_ws, size_t ws_size,
                              hipStream_t stream) {
  const float* feat = (const float*)d_in[0];
  const int*   src  = (const int*)d_in[1];
  const int*   dst  = (const int*)d_in[2];
  const int*   gid  = (const int*)d_in[3];
  const float* W1   = (const float*)d_in[4];
  const float* al1  = (const float*)d_in[5];
  const float* ar1  = (const float*)d_in[6];
  const float* b1   = (const float*)d_in[7];
  const float* W2   = (const float*)d_in[8];
  const float* al2  = (const float*)d_in[9];
  const float* ar2  = (const float*)d_in[10];
  const float* b2   = (const float*)d_in[11];
  const float* lw1  = (const float*)d_in[12];
  const float* lb1  = (const float*)d_in[13];
  const float* lw2  = (const float*)d_in[14];
  const float* lb2  = (const float*)d_in[15];
  float* out = (float*)d_out;

  float* ws = (float*)d_ws;
  size_t o = 0;
  float* ft1  = ws + o; o += (size_t)NN * F1;     // 12.8M floats
  float* ft2  = ws + o; o += (size_t)NN * D2_;    // 2.56M
  float* el1  = ws + o; o += (size_t)NN * H1_;
  float* er1  = ws + o; o += (size_t)NN * H1_;
  float* h1v  = ws + o; o += (size_t)NN * D1_;
  float* el2  = ws + o; o += NN;
  float* er2  = ws + o; o += NN;
  float* rbuf = ws + o; o += (size_t)GG * D2_;
  int* hist   = (int*)(ws + o); o += NN;
  int* rowptr = (int*)(ws + o); o += NN + 1;
  int* cursor = (int*)(ws + o); o += NN;
  int* ssrc   = (int*)(ws + o); o += EE;

  // ---- CSR build (shared by both layers) ----
  fill_u32<<<cdiv(NN,256),256,0,stream>>>((unsigned*)hist, 0u, NN);
  hist_k<<<cdiv(EE,256),256,0,stream>>>(dst, hist);
  scan_k<<<1,1024,0,stream>>>(hist, rowptr, cursor);
  scatter_k<<<cdiv(EE,256),256,0,stream>>>(src, dst, cursor, ssrc);

  // ---- layer 1 ----
  gemm_ft1<<<dim3(2, NN), 320, 0, stream>>>(feat, W1, ft1);
  elr1_kernel<<<cdiv((long long)NN*H1_*64,256),256,0,stream>>>(ft1, al1, ar1, el1, er1);
  l1_agg<<<NN, 640, 0, stream>>>(rowptr, ssrc, el1, er1, ft1, b1, h1v);

  // ---- layer 2 ----
  gemm_ft2<<<NN, 128, 0, stream>>>(h1v, W2, ft2);
  elr2_kernel<<<cdiv((long long)NN*64,256),256,0,stream>>>(ft2, al2, ar2, el2, er2);
  fill_u32<<<cdiv(GG*D2_,256),256,0,stream>>>((unsigned*)rbuf, 0u, GG*D2_);
  l2_agg<<<NN, 128, 0, stream>>>(rowptr, ssrc, el2, er2, ft2, b2, gid, (int*)rbuf);

  // ---- readout MLP ----
  final_mlp<<<GG, D2_, 0, stream>>>(rbuf, lw1, lb1, lw2, lb2, out);
}

// Round 3
// 401.796 us; speedup vs baseline: 2.9003x; 1.5275x over previous
//
#include <hip/hip_runtime.h>

#define NN 20000
#define EE 320000
#define GG 50
#define IN_ 64
#define H1_ 10
#define D1_ 64
#define D2_ 128
#define F1 640   /* H1_*D1_ */
#define NEG 0.2f

static inline int cdiv(long long a, int b){ return (int)((a + b - 1) / b); }

__device__ inline float lrelu(float x){ return x > 0.f ? x : NEG * x; }
__device__ inline float wmax64(float x){
  #pragma unroll
  for(int off = 32; off > 0; off >>= 1) x = fmaxf(x, __shfl_xor(x, off, 64));
  return x;
}
__device__ inline float wsum64(float x){
  #pragma unroll
  for(int off = 32; off > 0; off >>= 1) x += __shfl_xor(x, off, 64);
  return x;
}

__global__ void fill_u32(unsigned* p, unsigned v, int n){
  int i = blockIdx.x * blockDim.x + threadIdx.x;
  if(i < n) p[i] = v;
}

// ---------------- CSR build ----------------
__global__ void hist_k(const int* __restrict__ dst, int* __restrict__ hist){
  int e = blockIdx.x * blockDim.x + threadIdx.x;
  if(e < EE) atomicAdd(&hist[dst[e]], 1);
}

__global__ void scan_k(const int* __restrict__ hist, int* __restrict__ rowptr,
                       int* __restrict__ cursor){
  __shared__ int tot[1024];
  int t = threadIdx.x;
  int vals[20];
  int s = 0;
  #pragma unroll
  for(int i = 0; i < 20; i++){
    int idx = t * 20 + i;
    int v = idx < NN ? hist[idx] : 0;
    vals[i] = v; s += v;
  }
  tot[t] = s;
  __syncthreads();
  for(int off = 1; off < 1024; off <<= 1){
    int v = t >= off ? tot[t - off] : 0;
    __syncthreads();
    tot[t] += v;
    __syncthreads();
  }
  int run = tot[t] - s;
  #pragma unroll
  for(int i = 0; i < 20; i++){
    int idx = t * 20 + i;
    if(idx < NN){ rowptr[idx] = run; cursor[idx] = run; run += vals[i]; }
  }
  if(t == 1023) rowptr[NN] = tot[1023];
}

__global__ void scatter_k(const int* __restrict__ src, const int* __restrict__ dst,
                          int* __restrict__ cursor, int* __restrict__ ssrc){
  int e = blockIdx.x * blockDim.x + threadIdx.x;
  if(e >= EE) return;
  int pos = atomicAdd(&cursor[dst[e]], 1);
  ssrc[pos] = src[e];
}

// ---------------- GEMM1: ft1 = feat @ W1, fused el1/er1 ----------------
// grid (10 heads, 313 node-tiles), block 256. BM=64 BN=64 K=64.
__global__ __launch_bounds__(256) void gemm1(
    const float* __restrict__ feat, const float* __restrict__ W1,
    const float* __restrict__ al1, const float* __restrict__ ar1,
    float* __restrict__ ft1, float* __restrict__ el, float* __restrict__ er){
  __shared__ float AsT[64][68];  // [k][r]
  __shared__ float Bs[64][68];   // [k][c]
  int h = blockIdx.x;
  int n0 = blockIdx.y * 64;
  int tid = threadIdx.x;
  #pragma unroll
  for(int l = 0; l < 4; l++){
    int idx = tid + l * 256;
    int r = idx >> 4, c4 = (idx & 15) << 2;
    float4 v = make_float4(0.f,0.f,0.f,0.f);
    if(n0 + r < NN) v = *(const float4*)&feat[(size_t)(n0 + r) * IN_ + c4];
    AsT[c4+0][r] = v.x; AsT[c4+1][r] = v.y; AsT[c4+2][r] = v.z; AsT[c4+3][r] = v.w;
    float4 w = *(const float4*)&W1[(size_t)(idx >> 4) * F1 + h * 64 + c4];
    *(float4*)&Bs[idx >> 4][c4] = w;
  }
  __syncthreads();
  int tr = tid >> 4, tc = tid & 15;
  float acc[4][4];
  #pragma unroll
  for(int i = 0; i < 4; i++)
    #pragma unroll
    for(int j = 0; j < 4; j++) acc[i][j] = 0.f;
  #pragma unroll 8
  for(int k = 0; k < 64; k++){
    float4 a4 = *(const float4*)&AsT[k][tr << 2];
    float4 b4 = *(const float4*)&Bs[k][tc << 2];
    float av[4] = {a4.x, a4.y, a4.z, a4.w};
    float bv[4] = {b4.x, b4.y, b4.z, b4.w};
    #pragma unroll
    for(int i = 0; i < 4; i++)
      #pragma unroll
      for(int j = 0; j < 4; j++) acc[i][j] += av[i] * bv[j];
  }
  float al4[4], ar4[4];
  #pragma unroll
  for(int j = 0; j < 4; j++){
    al4[j] = al1[h * 64 + (tc << 2) + j];
    ar4[j] = ar1[h * 64 + (tc << 2) + j];
  }
  #pragma unroll
  for(int i = 0; i < 4; i++){
    int row = n0 + (tr << 2) + i;
    bool ok = row < NN;
    if(ok){
      float4 o = make_float4(acc[i][0], acc[i][1], acc[i][2], acc[i][3]);
      *(float4*)&ft1[(size_t)row * F1 + h * 64 + (tc << 2)] = o;
    }
    float e1 = acc[i][0]*al4[0] + acc[i][1]*al4[1] + acc[i][2]*al4[2] + acc[i][3]*al4[3];
    float e2 = acc[i][0]*ar4[0] + acc[i][1]*ar4[1] + acc[i][2]*ar4[2] + acc[i][3]*ar4[3];
    #pragma unroll
    for(int off = 1; off < 16; off <<= 1){
      e1 += __shfl_xor(e1, off, 64);
      e2 += __shfl_xor(e2, off, 64);
    }
    if(tc == 0 && ok){ el[row * H1_ + h] = e1; er[row * H1_ + h] = e2; }
  }
}

// ---------------- attention coefficients, layer 1 ----------------
// wave per (dn, h); scores cached in registers for deg <= 256
__global__ void l1_attn(const int* __restrict__ rowptr, const int* __restrict__ ssrc,
                        const float* __restrict__ el, const float* __restrict__ er,
                        float* __restrict__ a1){
  int gw = (blockIdx.x * blockDim.x + threadIdx.x) >> 6;
  int lane = threadIdx.x & 63;
  if(gw >= NN * H1_) return;
  int dn = gw / H1_, h = gw - dn * H1_;
  int base = rowptr[dn], deg = rowptr[dn + 1] - base;
  if(deg == 0) return;
  float er_h = er[dn * H1_ + h];
  if(deg <= 256){
    float ax[4] = {-INFINITY, -INFINITY, -INFINITY, -INFINITY};
    float mx = -INFINITY;
    #pragma unroll
    for(int c = 0; c < 4; c++){
      int i = (c << 6) + lane;
      if(i < deg){
        ax[c] = lrelu(el[ssrc[base + i] * H1_ + h] + er_h);
        mx = fmaxf(mx, ax[c]);
      }
    }
    mx = wmax64(mx);
    float sm = 0.f;
    #pragma unroll
    for(int c = 0; c < 4; c++){
      int i = (c << 6) + lane;
      if(i < deg){ ax[c] = expf(ax[c] - mx); sm += ax[c]; }
    }
    sm = wsum64(sm);
    float inv = 1.f / sm;
    #pragma unroll
    for(int c = 0; c < 4; c++){
      int i = (c << 6) + lane;
      if(i < deg) a1[(size_t)h * EE + base + i] = ax[c] * inv;
    }
  } else {
    float mx = -INFINITY;
    for(int i = lane; i < deg; i += 64)
      mx = fmaxf(mx, lrelu(el[ssrc[base + i] * H1_ + h] + er_h));
    mx = wmax64(mx);
    float sm = 0.f;
    for(int i = lane; i < deg; i += 64)
      sm += expf(lrelu(el[ssrc[base + i] * H1_ + h] + er_h) - mx);
    sm = wsum64(sm);
    float inv = 1.f / sm;
    for(int i = lane; i < deg; i += 64)
      a1[(size_t)h * EE + base + i] =
          expf(lrelu(el[ssrc[base + i] * H1_ + h] + er_h) - mx) * inv;
  }
}

// ---------------- aggregation layer 1 (+bias+relu+head-sum) ----------------
// block 640 = 10 waves (one per head); 4 edge-groups x 16 lanes x float4
__global__ __launch_bounds__(640) void l1_agg(
    const int* __restrict__ rowptr, const int* __restrict__ ssrc,
    const float* __restrict__ a1, const float* __restrict__ ft1,
    const float* __restrict__ b1, float* __restrict__ h1v){
  __shared__ float sdata[F1];
  int dn = blockIdx.x;
  int tid = threadIdx.x;
  int h = tid >> 6, lane = tid & 63, g = lane >> 4, d4 = lane & 15;
  int base = rowptr[dn], deg = rowptr[dn + 1] - base;
  float4 acc = make_float4(0.f, 0.f, 0.f, 0.f);
  const float* ah = a1 + (size_t)h * EE + base;
  int i = g;
  int sn = 0; float av = 0.f;
  if(i < deg){ sn = ssrc[base + i]; av = ah[i]; }
  while(i < deg){
    int in_ = i + 4;
    int sn_n = 0; float av_n = 0.f;
    if(in_ < deg){ sn_n = ssrc[base + in_]; av_n = ah[in_]; }
    float4 f = *(const float4*)&ft1[(size_t)sn * F1 + h * 64 + (d4 << 2)];
    acc.x += av * f.x; acc.y += av * f.y; acc.z += av * f.z; acc.w += av * f.w;
    i = in_; sn = sn_n; av = av_n;
  }
  #pragma unroll
  for(int off = 16; off <= 32; off <<= 1){
    acc.x += __shfl_xor(acc.x, off, 64);
    acc.y += __shfl_xor(acc.y, off, 64);
    acc.z += __shfl_xor(acc.z, off, 64);
    acc.w += __shfl_xor(acc.w, off, 64);
  }
  if(g == 0){
    int d = d4 << 2;
    float v0 = acc.x + b1[h * 64 + d + 0];
    float v1 = acc.y + b1[h * 64 + d + 1];
    float v2 = acc.z + b1[h * 64 + d + 2];
    float v3 = acc.w + b1[h * 64 + d + 3];
    sdata[h * 64 + d + 0] = v0 > 0.f ? v0 : 0.f;
    sdata[h * 64 + d + 1] = v1 > 0.f ? v1 : 0.f;
    sdata[h * 64 + d + 2] = v2 > 0.f ? v2 : 0.f;
    sdata[h * 64 + d + 3] = v3 > 0.f ? v3 : 0.f;
  }
  __syncthreads();
  if(tid < 64){
    float s = 0.f;
    #pragma unroll
    for(int hh = 0; hh < H1_; hh++) s += sdata[hh * 64 + tid];
    h1v[dn * D1_ + tid] = s;
  }
}

// ---------------- GEMM2: ft2 = h1v @ W2, fused el2/er2 ----------------
// grid 625, block 256. BM=32 BN=128 K=64.
__global__ __launch_bounds__(256) void gemm2(
    const float* __restrict__ h1v, const float* __restrict__ W2,
    const float* __restrict__ al2, const float* __restrict__ ar2,
    float* __restrict__ ft2, float* __restrict__ el, float* __restrict__ er){
  __shared__ float AsT[64][36];   // [k][r], r<32
  __shared__ float Bs[64][132];   // [k][c]
  int n0 = blockIdx.x * 32;
  int tid = threadIdx.x;
  #pragma unroll
  for(int l = 0; l < 2; l++){
    int idx = tid + l * 256;
    int r = idx >> 4, c4 = (idx & 15) << 2;
    float4 v = make_float4(0.f,0.f,0.f,0.f);
    if(n0 + r < NN) v = *(const float4*)&h1v[(size_t)(n0 + r) * D1_ + c4];
    AsT[c4+0][r] = v.x; AsT[c4+1][r] = v.y; AsT[c4+2][r] = v.z; AsT[c4+3][r] = v.w;
  }
  #pragma unroll
  for(int l = 0; l < 8; l++){
    int idx = tid + l * 256;
    int k = idx >> 5, c4 = (idx & 31) << 2;
    *(float4*)&Bs[k][c4] = *(const float4*)&W2[(size_t)k * D2_ + c4];
  }
  __syncthreads();
  int tr = tid >> 5, tc = tid & 31;
  float acc[4][4];
  #pragma unroll
  for(int i = 0; i < 4; i++)
    #pragma unroll
    for(int j = 0; j < 4; j++) acc[i][j] = 0.f;
  #pragma unroll 8
  for(int k = 0; k < 64; k++){
    float4 a4 = *(const float4*)&AsT[k][tr << 2];
    float4 b4 = *(const float4*)&Bs[k][tc << 2];
    float av[4] = {a4.x, a4.y, a4.z, a4.w};
    float bv[4] = {b4.x, b4.y, b4.z, b4.w};
    #pragma unroll
    for(int i = 0; i < 4; i++)
      #pragma unroll
      for(int j = 0; j < 4; j++) acc[i][j] += av[i] * bv[j];
  }
  float al4[4], ar4[4];
  #pragma unroll
  for(int j = 0; j < 4; j++){
    al4[j] = al2[(tc << 2) + j];
    ar4[j] = ar2[(tc << 2) + j];
  }
  #pragma unroll
  for(int i = 0; i < 4; i++){
    int row = n0 + (tr << 2) + i;
    bool ok = row < NN;
    if(ok){
      float4 o = make_float4(acc[i][0], acc[i][1], acc[i][2], acc[i][3]);
      *(float4*)&ft2[(size_t)row * D2_ + (tc << 2)] = o;
    }
    float e1 = acc[i][0]*al4[0] + acc[i][1]*al4[1] + acc[i][2]*al4[2] + acc[i][3]*al4[3];
    float e2 = acc[i][0]*ar4[0] + acc[i][1]*ar4[1] + acc[i][2]*ar4[2] + acc[i][3]*ar4[3];
    #pragma unroll
    for(int off = 1; off < 32; off <<= 1){
      e1 += __shfl_xor(e1, off, 64);
      e2 += __shfl_xor(e2, off, 64);
    }
    if(tc == 0 && ok){ el[row] = e1; er[row] = e2; }
  }
}

// ---------------- attention coefficients, layer 2 ----------------
__global__ void l2_attn(const int* __restrict__ rowptr, const int* __restrict__ ssrc,
                        const float* __restrict__ el, const float* __restrict__ er,
                        float* __restrict__ a2){
  int gw = (blockIdx.x * blockDim.x + threadIdx.x) >> 6;
  int lane = threadIdx.x & 63;
  if(gw >= NN) return;
  int dn = gw;
  int base = rowptr[dn], deg = rowptr[dn + 1] - base;
  if(deg == 0) return;
  float er_d = er[dn];
  if(deg <= 256){
    float ax[4] = {-INFINITY, -INFINITY, -INFINITY, -INFINITY};
    float mx = -INFINITY;
    #pragma unroll
    for(int c = 0; c < 4; c++){
      int i = (c << 6) + lane;
      if(i < deg){
        ax[c] = lrelu(el[ssrc[base + i]] + er_d);
        mx = fmaxf(mx, ax[c]);
      }
    }
    mx = wmax64(mx);
    float sm = 0.f;
    #pragma unroll
    for(int c = 0; c < 4; c++){
      int i = (c << 6) + lane;
      if(i < deg){ ax[c] = expf(ax[c] - mx); sm += ax[c]; }
    }
    sm = wsum64(sm);
    float inv = 1.f / sm;
    #pragma unroll
    for(int c = 0; c < 4; c++){
      int i = (c << 6) + lane;
      if(i < deg) a2[base + i] = ax[c] * inv;
    }
  } else {
    float mx = -INFINITY;
    for(int i = lane; i < deg; i += 64)
      mx = fmaxf(mx, lrelu(el[ssrc[base + i]] + er_d));
    mx = wmax64(mx);
    float sm = 0.f;
    for(int i = lane; i < deg; i += 64)
      sm += expf(lrelu(el[ssrc[base + i]] + er_d) - mx);
    sm = wsum64(sm);
    float inv = 1.f / sm;
    for(int i = lane; i < deg; i += 64)
      a2[base + i] = expf(lrelu(el[ssrc[base + i]] + er_d) - mx) * inv;
  }
}

// ---------------- aggregation layer 2 (+bias+relu+graph max) ----------------
// block 128 = 2 waves (d-halves); 4 edge-groups x 16 lanes x float4
__global__ __launch_bounds__(128) void l2_agg(
    const int* __restrict__ rowptr, const int* __restrict__ ssrc,
    const float* __restrict__ a2, const float* __restrict__ ft2,
    const float* __restrict__ b2, const int* __restrict__ gid,
    int* __restrict__ rbuf){
  int dn = blockIdx.x;
  int tid = threadIdx.x;
  int w = tid >> 6, lane = tid & 63, g = lane >> 4, d4 = lane & 15;
  int d = w * 64 + (d4 << 2);
  int base = rowptr[dn], deg = rowptr[dn + 1] - base;
  float4 acc = make_float4(0.f, 0.f, 0.f, 0.f);
  int i = g;
  int sn = 0; float av = 0.f;
  if(i < deg){ sn = ssrc[base + i]; av = a2[base + i]; }
  while(i < deg){
    int in_ = i + 4;
    int sn_n = 0; float av_n = 0.f;
    if(in_ < deg){ sn_n = ssrc[base + in_]; av_n = a2[base + in_]; }
    float4 f = *(const float4*)&ft2[(size_t)sn * D2_ + d];
    acc.x += av * f.x; acc.y += av * f.y; acc.z += av * f.z; acc.w += av * f.w;
    i = in_; sn = sn_n; av = av_n;
  }
  #pragma unroll
  for(int off = 16; off <= 32; off <<= 1){
    acc.x += __shfl_xor(acc.x, off, 64);
    acc.y += __shfl_xor(acc.y, off, 64);
    acc.z += __shfl_xor(acc.z, off, 64);
    acc.w += __shfl_xor(acc.w, off, 64);
  }
  if(g == 0){
    int gb = gid[dn] * D2_ + d;
    float v0 = acc.x + b2[d + 0]; v0 = v0 > 0.f ? v0 : 0.f;
    float v1 = acc.y + b2[d + 1]; v1 = v1 > 0.f ? v1 : 0.f;
    float v2 = acc.z + b2[d + 2]; v2 = v2 > 0.f ? v2 : 0.f;
    float v3 = acc.w + b2[d + 3]; v3 = v3 > 0.f ? v3 : 0.f;
    atomicMax(&rbuf[gb + 0], __float_as_int(v0));
    atomicMax(&rbuf[gb + 1], __float_as_int(v1));
    atomicMax(&rbuf[gb + 2], __float_as_int(v2));
    atomicMax(&rbuf[gb + 3], __float_as_int(v3));
  }
}

__global__ void final_mlp(const float* __restrict__ r, const float* __restrict__ lw1,
                          const float* __restrict__ lb1, const float* __restrict__ lw2,
                          const float* __restrict__ lb2, float* __restrict__ out){
  __shared__ float rv[D2_];
  __shared__ float t[D2_];
  int g = blockIdx.x, j = threadIdx.x;
  rv[j] = r[g * D2_ + j];
  __syncthreads();
  float acc = lb1[j];
  #pragma unroll
  for(int k = 0; k < D2_; k++) acc += rv[k] * lw1[k * D2_ + j];
  acc = acc > 0.f ? acc : 0.f;
  t[j] = acc * lw2[j];
  __syncthreads();
  for(int off = 64; off > 0; off >>= 1){
    if(j < off) t[j] += t[j + off];
    __syncthreads();
  }
  if(j == 0){
    float v = t[0] + lb2[0];
    out[g] = v > 0.f ? v : 0.f;
  }
}

extern "C" void kernel_launch(void* const* d_in, const int* in_sizes, int n_in,
                              void* d_out, int out_size, void* d_ws, size_t ws_size,
                              hipStream_t stream) {
  const float* feat = (const float*)d_in[0];
  const int*   src  = (const int*)d_in[1];
  const int*   dst  = (const int*)d_in[2];
  const int*   gid  = (const int*)d_in[3];
  const float* W1   = (const float*)d_in[4];
  const float* al1  = (const float*)d_in[5];
  const float* ar1  = (const float*)d_in[6];
  const float* b1   = (const float*)d_in[7];
  const float* W2   = (const float*)d_in[8];
  const float* al2  = (const float*)d_in[9];
  const float* ar2  = (const float*)d_in[10];
  const float* b2   = (const float*)d_in[11];
  const float* lw1  = (const float*)d_in[12];
  const float* lb1  = (const float*)d_in[13];
  const float* lw2  = (const float*)d_in[14];
  const float* lb2  = (const float*)d_in[15];
  float* out = (float*)d_out;

  float* ws = (float*)d_ws;
  size_t o = 0;
  float* ft1  = ws + o; o += (size_t)NN * F1;     // 12.8M
  float* ft2  = ws + o; o += (size_t)NN * D2_;    // 2.56M
  float* a1   = ws + o; o += (size_t)H1_ * EE;    // 3.2M
  float* a2   = ws + o; o += EE;                  // 0.32M
  float* el1  = ws + o; o += (size_t)NN * H1_;
  float* er1  = ws + o; o += (size_t)NN * H1_;
  float* h1v  = ws + o; o += (size_t)NN * D1_;
  float* el2  = ws + o; o += NN;
  float* er2  = ws + o; o += NN;
  float* rbuf = ws + o; o += (size_t)GG * D2_;
  int* hist   = (int*)(ws + o); o += NN;
  int* rowptr = (int*)(ws + o); o += NN + 1;
  int* cursor = (int*)(ws + o); o += NN;
  int* ssrc   = (int*)(ws + o); o += EE;

  // ---- CSR build ----
  fill_u32<<<cdiv(NN,256),256,0,stream>>>((unsigned*)hist, 0u, NN);
  hist_k<<<cdiv(EE,256),256,0,stream>>>(dst, hist);
  scan_k<<<1,1024,0,stream>>>(hist, rowptr, cursor);
  scatter_k<<<cdiv(EE,256),256,0,stream>>>(src, dst, cursor, ssrc);

  // ---- layer 1 ----
  gemm1<<<dim3(H1_, cdiv(NN,64)), 256, 0, stream>>>(feat, W1, al1, ar1, ft1, el1, er1);
  l1_attn<<<cdiv((long long)NN*H1_*64,256),256,0,stream>>>(rowptr, ssrc, el1, er1, a1);
  l1_agg<<<NN, 640, 0, stream>>>(rowptr, ssrc, a1, ft1, b1, h1v);

  // ---- layer 2 ----
  gemm2<<<cdiv(NN,32), 256, 0, stream>>>(h1v, W2, al2, ar2, ft2, el2, er2);
  l2_attn<<<cdiv((long long)NN*64,256),256,0,stream>>>(rowptr, ssrc, el2, er2, a2);
  fill_u32<<<cdiv(GG*D2_,256),256,0,stream>>>((unsigned*)rbuf, 0u, GG*D2_);
  l2_agg<<<NN, 128, 0, stream>>>(rowptr, ssrc, a2, ft2, b2, gid, (int*)rbuf);

  // ---- readout MLP ----
  final_mlp<<<GG, D2_, 0, stream>>>(rbuf, lw1, lb1, lw2, lb2, out);
}